// Round 2
// baseline (4659.487 us; speedup 1.0000x reference)
//
#include <hip/hip_runtime.h>
#include <math.h>

// Gated delta-rule linear attention (Qwen3.5 GatedDeltaNet), fp32 baseline.
// Phase A (parallel over chunks): per-chunk preprocessing.
// Phase B (sequential scan over 64 chunks, parallel over bh * 8 dv-blocks).
// (b,h) pairs are processed in groups sized so the per-group workspace fits
// ws_size: per-bh footprint = 64 chunks * (4*8192 + 4096 + 1) floats = 9.44 MB.

namespace {
constexpr int Bn = 2, Sn = 4096, Hn = 16, DKn = 128, DVn = 128, Cn = 64, Nn = 64;
constexpr long CH = 8192;                 // 64*128 floats per chunk array
constexpr long PER_CHUNK_F = 4 * CH + 4096 + 1;   // QG,KC,KDT,VC + ATT + GL
}

__global__ __launch_bounds__(512) void gdn_phaseA(
    const float* __restrict__ q, const float* __restrict__ k,
    const float* __restrict__ v, const float* __restrict__ g,
    const float* __restrict__ beta, float* __restrict__ ws,
    int bh0, long ncp)
{
  const long OFF_QG  = 0;
  const long OFF_KC  = ncp * CH;
  const long OFF_KDT = 2 * ncp * CH;
  const long OFF_VC  = 3 * ncp * CH;
  const long OFF_ATT = 4 * ncp * CH;
  const long OFF_GL  = 4 * ncp * CH + ncp * 4096;

  __shared__ float sA[64][132];   // l2-normalized k
  __shared__ float sQ[64][132];   // l2-normalized, scaled q
  __shared__ float sM[64][68];    // strict-lower M
  __shared__ float s_gc[64], s_beta[64], s_egc[64], s_ekd[64];

  const int t  = threadIdx.x;
  const int pl = blockIdx.x;              // local chunk index within pass
  const int p  = bh0 * Nn + pl;           // global chunk id = ((b*H+h)*N + n)
  const int n  = p % Nn;
  const int bh = p / Nn;
  const int h  = bh % Hn;
  const int b  = bh / Hn;
  const long base   = (((long)b * Sn + (long)n * Cn) * Hn + h) * DKn;
  const long rowstr = (long)Hn * DKn;                    // 2048
  const long gbase  = ((long)b * Sn + (long)n * Cn) * Hn + h;

  // ---- smalls: g cumsum, beta, exp tables ----
  if (t < 64) {
    s_beta[t] = beta[gbase + (long)t * Hn];
    sM[0][t]  = g[gbase + (long)t * Hn];   // stash raw g (sM rewritten later)
  }
  __syncthreads();
  if (t == 0) {
    float run = 0.f;
    #pragma unroll
    for (int c = 0; c < 64; ++c) { run += sM[0][c]; s_gc[c] = run; }
    ws[OFF_GL + pl] = expf(run);           // exp(g_last)
  }
  __syncthreads();
  if (t < 64) {
    s_egc[t] = expf(s_gc[t]);
    s_ekd[t] = expf(s_gc[63] - s_gc[t]);
  }

  // ---- load k, q (float4) ----
  for (int i = 0; i < 4; ++i) {
    int idx = t + 512 * i;                // float4 index 0..2047
    int c = idx >> 5;
    int d = (idx & 31) << 2;
    float4 kv = *(const float4*)(k + base + (long)c * rowstr + d);
    float4 qv = *(const float4*)(q + base + (long)c * rowstr + d);
    *(float4*)&sA[c][d] = kv;
    *(float4*)&sQ[c][d] = qv;
  }
  __syncthreads();

  // ---- l2norm rows (8 threads/row) ----
  {
    const int c = t >> 3, l8 = t & 7;
    float sk = 0.f, sq = 0.f;
    #pragma unroll
    for (int i = 0; i < 16; ++i) {
      float a  = sA[c][l8 * 16 + i]; sk += a * a;
      float b2 = sQ[c][l8 * 16 + i]; sq += b2 * b2;
    }
    #pragma unroll
    for (int m = 1; m < 8; m <<= 1) {
      sk += __shfl_xor(sk, m, 64);
      sq += __shfl_xor(sq, m, 64);
    }
    const float rk = rsqrtf(sk + 1e-6f);
    const float rq = rsqrtf(sq + 1e-6f) * 0.08838834764831845f;  // * Dk^-0.5
    #pragma unroll
    for (int i = 0; i < 16; ++i) {
      sA[c][l8 * 16 + i] *= rk;
      sQ[c][l8 * 16 + i] *= rq;
    }
  }
  __syncthreads();

  // ---- M (strict lower, for solve) and attn (tril incl diag, to ws) ----
  {
    const int d = t & 63;
    const int w = t >> 6;                  // 0..7
    float ma[8] = {0,0,0,0,0,0,0,0};
    float qa[8] = {0,0,0,0,0,0,0,0};
    for (int dd = 0; dd < 128; dd += 4) {
      float4 va = *(const float4*)&sA[d][dd];
      #pragma unroll
      for (int kk = 0; kk < 8; ++kk) {
        const int c = w + 8 * kk;
        float4 ka = *(const float4*)&sA[c][dd];
        float4 qv = *(const float4*)&sQ[c][dd];
        ma[kk] += ka.x*va.x + ka.y*va.y + ka.z*va.z + ka.w*va.w;
        qa[kk] += qv.x*va.x + qv.y*va.y + qv.z*va.z + qv.w*va.w;
      }
    }
    float* att = ws + OFF_ATT + (long)pl * 4096;
    #pragma unroll
    for (int kk = 0; kk < 8; ++kk) {
      const int c = w + 8 * kk;
      const float dec = (c >= d) ? expf(s_gc[c] - s_gc[d]) : 0.f;
      att[c * 64 + d] = qa[kk] * dec;
      sM[c][d] = (c > d) ? ma[kk] * s_beta[c] * dec : 0.f;
    }
  }

  // ---- q_g and kd^T to ws (reads only sA/sQ; no LDS hazard with M step) ----
  {
    float* qg  = ws + OFF_QG  + (long)pl * CH;
    float* kdt = ws + OFF_KDT + (long)pl * CH;
    #pragma unroll
    for (int i = 0; i < 16; ++i) {
      int o = t + 512 * i;
      int c = o >> 7, d = o & 127;
      qg[o] = sQ[c][d] * s_egc[c];
      int d2 = o >> 6, c2 = o & 63;
      kdt[o] = sA[c2][d2] * s_ekd[c2];     // kdT[d][c]
    }
  }
  __syncthreads();

  // ---- forward substitution (I+M) X = RHS, column-per-thread in registers ----
  // cols 0..127: RHS = k_beta * exp(gc)  -> k_cum
  // cols 128..255: RHS = v * beta        -> v_c
  if (t < 256) {
    float X[64];
    const int j = t;
    if (j < 128) {
      #pragma unroll
      for (int i = 0; i < 64; ++i) X[i] = sA[i][j] * s_beta[i] * s_egc[i];
    } else {
      const int jj = j - 128;
      #pragma unroll
      for (int i = 0; i < 64; ++i)
        X[i] = v[base + (long)i * rowstr + jj] * s_beta[i];
    }
    #pragma unroll
    for (int i = 1; i < 64; ++i) {
      float s0 = 0.f, s1 = 0.f;
      #pragma unroll
      for (int l = 0; l < i - 1; l += 2) {
        s0 += sM[i][l]     * X[l];
        s1 += sM[i][l + 1] * X[l + 1];
      }
      if ((i & 1) != 0) s0 += sM[i][i - 1] * X[i - 1];
      X[i] = X[i] - s0 - s1;
    }
    float* dst = (j < 128) ? (ws + OFF_KC + (long)pl * CH + j)
                           : (ws + OFF_VC + (long)pl * CH + (j - 128));
    #pragma unroll
    for (int i = 0; i < 64; ++i) dst[(long)i * 128] = X[i];
  }
}

__global__ __launch_bounds__(512) void gdn_phaseB(
    const float* __restrict__ ws, float* __restrict__ out,
    int bh0, long ncp)
{
  const long OFF_KC  = ncp * CH;
  const long OFF_KDT = 2 * ncp * CH;
  const long OFF_VC  = 3 * ncp * CH;
  const long OFF_ATT = 4 * ncp * CH;
  const long OFF_GL  = 4 * ncp * CH + ncp * 4096;

  __shared__ float st[16][132];     // state[j][d], j = dv within block
  __shared__ float su[16][68];      // u[j][c]
  __shared__ float buf[64 * 128];   // staged k_cum / q_g / kdT
  __shared__ float abuf[64 * 64];   // staged attn

  const int t   = threadIdx.x;
  const int blk = blockIdx.x;
  const int jb  = blk & 7;          // dv block (16 cols)
  const int bhl = blk >> 3;         // local bh within pass
  const int bh  = bh0 + bhl;
  const int h   = bh % Hn;
  const int b   = bh / Hn;
  const int j   = t & 15;           // dv within block
  const int cg  = t >> 4;           // 0..31

  for (int i = t; i < 16 * 132; i += 512) (&st[0][0])[i] = 0.f;
  __syncthreads();

  for (int n = 0; n < Nn; ++n) {
    const long pl = (long)bhl * Nn + n;
    const float gl = ws[OFF_GL + pl];

    // stage k_cum
    {
      const float4* src  = (const float4*)(ws + OFF_KC + pl * CH);
      float4*       dstb = (float4*)buf;
      #pragma unroll
      for (int i = 0; i < 4; ++i) dstb[t + 512 * i] = src[t + 512 * i];
    }
    __syncthreads();

    // m1: u = v_c - k_cum @ state
    {
      const int c0 = cg, c1 = cg + 32;
      const float* b0 = buf + c0 * 128;
      const float* b1 = buf + c1 * 128;
      float a0 = 0.f, a1 = 0.f;
      #pragma unroll
      for (int d = 0; d < 128; d += 4) {
        float4 sv = *(const float4*)&st[j][d];
        float4 x0 = *(const float4*)(b0 + d);
        float4 x1 = *(const float4*)(b1 + d);
        a0 += x0.x*sv.x + x0.y*sv.y + x0.z*sv.z + x0.w*sv.w;
        a1 += x1.x*sv.x + x1.y*sv.y + x1.z*sv.z + x1.w*sv.w;
      }
      su[j][c0] = ws[OFF_VC + pl * CH + c0 * 128 + jb * 16 + j] - a0;
      su[j][c1] = ws[OFF_VC + pl * CH + c1 * 128 + jb * 16 + j] - a1;
    }
    __syncthreads();

    // stage q_g + attn
    {
      const float4* src  = (const float4*)(ws + pl * CH);   // OFF_QG == 0
      float4*       dstb = (float4*)buf;
      #pragma unroll
      for (int i = 0; i < 4; ++i) dstb[t + 512 * i] = src[t + 512 * i];
      const float4* asrc = (const float4*)(ws + OFF_ATT + pl * 4096);
      float4*       adst = (float4*)abuf;
      #pragma unroll
      for (int i = 0; i < 2; ++i) adst[t + 512 * i] = asrc[t + 512 * i];
    }
    __syncthreads();

    // m2: out = q_g @ state + attn @ u
    {
      const int c0 = cg, c1 = cg + 32;
      const float* b0 = buf + c0 * 128;
      const float* b1 = buf + c1 * 128;
      float a0 = 0.f, a1 = 0.f;
      #pragma unroll
      for (int d = 0; d < 128; d += 4) {
        float4 sv = *(const float4*)&st[j][d];
        float4 x0 = *(const float4*)(b0 + d);
        float4 x1 = *(const float4*)(b1 + d);
        a0 += x0.x*sv.x + x0.y*sv.y + x0.z*sv.z + x0.w*sv.w;
        a1 += x1.x*sv.x + x1.y*sv.y + x1.z*sv.z + x1.w*sv.w;
      }
      const float* ac0 = abuf + c0 * 64;
      const float* ac1 = abuf + c1 * 64;
      #pragma unroll
      for (int e = 0; e < 64; e += 4) {
        float4 uv = *(const float4*)&su[j][e];
        float4 v0 = *(const float4*)(ac0 + e);
        float4 v1 = *(const float4*)(ac1 + e);
        a0 += v0.x*uv.x + v0.y*uv.y + v0.z*uv.z + v0.w*uv.w;
        a1 += v1.x*uv.x + v1.y*uv.y + v1.z*uv.z + v1.w*uv.w;
      }
      const long obase = (((long)b * Sn + (long)n * Cn) * Hn + h) * DVn + jb * 16 + j;
      out[obase + (long)c0 * Hn * DVn] = a0;
      out[obase + (long)c1 * Hn * DVn] = a1;
    }
    __syncthreads();

    // stage kdT
    {
      const float4* src  = (const float4*)(ws + OFF_KDT + pl * CH);
      float4*       dstb = (float4*)buf;
      #pragma unroll
      for (int i = 0; i < 4; ++i) dstb[t + 512 * i] = src[t + 512 * i];
    }
    __syncthreads();

    // m3: state = gl*state + kd^T @ u
    {
      float a0 = 0.f, a1 = 0.f, a2 = 0.f, a3 = 0.f;
      const float* bd0 = buf + (cg +  0) * 64;
      const float* bd1 = buf + (cg + 32) * 64;
      const float* bd2 = buf + (cg + 64) * 64;
      const float* bd3 = buf + (cg + 96) * 64;
      #pragma unroll
      for (int cc = 0; cc < 64; cc += 4) {
        float4 uv = *(const float4*)&su[j][cc];
        float4 k0 = *(const float4*)(bd0 + cc);
        float4 k1 = *(const float4*)(bd1 + cc);
        float4 k2 = *(const float4*)(bd2 + cc);
        float4 k3 = *(const float4*)(bd3 + cc);
        a0 += k0.x*uv.x + k0.y*uv.y + k0.z*uv.z + k0.w*uv.w;
        a1 += k1.x*uv.x + k1.y*uv.y + k1.z*uv.z + k1.w*uv.w;
        a2 += k2.x*uv.x + k2.y*uv.y + k2.z*uv.z + k2.w*uv.w;
        a3 += k3.x*uv.x + k3.y*uv.y + k3.z*uv.z + k3.w*uv.w;
      }
      st[j][cg +  0] = gl * st[j][cg +  0] + a0;
      st[j][cg + 32] = gl * st[j][cg + 32] + a1;
      st[j][cg + 64] = gl * st[j][cg + 64] + a2;
      st[j][cg + 96] = gl * st[j][cg + 96] + a3;
    }
    __syncthreads();
  }
}

extern "C" void kernel_launch(void* const* d_in, const int* in_sizes, int n_in,
                              void* d_out, int out_size, void* d_ws, size_t ws_size,
                              hipStream_t stream) {
  (void)in_sizes; (void)n_in; (void)out_size;
  const float* q    = (const float*)d_in[0];
  const float* k    = (const float*)d_in[1];
  const float* v    = (const float*)d_in[2];
  const float* g    = (const float*)d_in[3];
  const float* beta = (const float*)d_in[4];
  float* ws  = (float*)d_ws;
  float* out = (float*)d_out;

  const int NBH = Bn * Hn;                          // 32
  const long per_bh_bytes = (long)Nn * PER_CHUNK_F * 4;   // 9,437,444*... ~9.44 MB
  long fit = (long)(ws_size / (size_t)per_bh_bytes);
  int G = (int)(fit < 1 ? 1 : (fit > NBH ? NBH : fit));   // bh per pass
  const long ncp = (long)G * Nn;                    // chunk capacity per pass

  for (int bh0 = 0; bh0 < NBH; bh0 += G) {
    const int grp = (bh0 + G <= NBH) ? G : (NBH - bh0);
    hipLaunchKernelGGL(gdn_phaseA, dim3(grp * Nn), dim3(512), 0, stream,
                       q, k, v, g, beta, ws, bh0, ncp);
    hipLaunchKernelGGL(gdn_phaseB, dim3(grp * 8), dim3(512), 0, stream,
                       ws, out, bh0, ncp);
  }
}

// Round 3
// 3498.060 us; speedup vs baseline: 1.3320x; 1.3320x over previous
//
#include <hip/hip_runtime.h>
#include <math.h>

// Gated delta-rule linear attention (Qwen3.5 GatedDeltaNet), fp32.
// Phase A (parallel over chunks, 256 thr, launch_bounds(256,1) to avoid
//   VGPR spills in the register-resident forward substitution).
// Phase B (sequential scan, async global_load_lds staging, 3 barriers/iter).

namespace {
constexpr int Bn = 2, Sn = 4096, Hn = 16, DKn = 128, DVn = 128, Cn = 64, Nn = 64;
constexpr long CH = 8192;                 // 64*128 floats per chunk array
constexpr long PER_CHUNK_F = 4 * CH + 4096 + 1;   // QG,KC,KDT,VC + ATT + GL
}

__device__ __forceinline__ void gl_lds16(const float* g, float* l) {
  __builtin_amdgcn_global_load_lds(
      (const __attribute__((address_space(1))) void*)g,
      (__attribute__((address_space(3))) void*)l, 16, 0, 0);
}

__global__ __launch_bounds__(256, 1) void gdn_phaseA(
    const float* __restrict__ q, const float* __restrict__ k,
    const float* __restrict__ v, const float* __restrict__ g,
    const float* __restrict__ beta, float* __restrict__ ws,
    int bh0, long ncp)
{
  const long OFF_KC  = ncp * CH;
  const long OFF_KDT = 2 * ncp * CH;
  const long OFF_VC  = 3 * ncp * CH;
  const long OFF_ATT = 4 * ncp * CH;
  const long OFF_GL  = 4 * ncp * CH + ncp * 4096;

  __shared__ float sA[64][132];   // l2-normalized k
  __shared__ float sQ[64][132];   // l2-normalized, scaled q
  __shared__ float sM[64][65];    // strict-lower M
  __shared__ float s_gc[64], s_beta[64], s_egc[64], s_ekd[64];

  const int t  = threadIdx.x;
  const int pl = blockIdx.x;              // local chunk index within pass
  const int p  = bh0 * Nn + pl;
  const int n  = p % Nn;
  const int bh = p / Nn;
  const int h  = bh % Hn;
  const int b  = bh / Hn;
  const long base   = (((long)b * Sn + (long)n * Cn) * Hn + h) * DKn;
  const long rowstr = (long)Hn * DKn;                    // 2048
  const long gbase  = ((long)b * Sn + (long)n * Cn) * Hn + h;

  // ---- smalls: g cumsum, beta, exp tables ----
  if (t < 64) {
    s_beta[t] = beta[gbase + (long)t * Hn];
    sM[0][t]  = g[gbase + (long)t * Hn];   // stash raw g (sM rewritten later)
  }
  __syncthreads();
  if (t == 0) {
    float run = 0.f;
    #pragma unroll
    for (int c = 0; c < 64; ++c) { run += sM[0][c]; s_gc[c] = run; }
    ws[OFF_GL + pl] = expf(run);           // exp(g_last)
  }
  __syncthreads();
  if (t < 64) {
    s_egc[t] = expf(s_gc[t]);
    s_ekd[t] = expf(s_gc[63] - s_gc[t]);
  }

  // ---- load k, q (float4, 8 per thread) ----
  #pragma unroll
  for (int i = 0; i < 8; ++i) {
    int idx = t + 256 * i;                // float4 index 0..2047
    int c = idx >> 5;
    int d = (idx & 31) << 2;
    *(float4*)&sA[c][d] = *(const float4*)(k + base + (long)c * rowstr + d);
    *(float4*)&sQ[c][d] = *(const float4*)(q + base + (long)c * rowstr + d);
  }
  __syncthreads();

  // ---- l2norm rows (4 threads/row, 32 elems each) ----
  {
    const int c = t >> 2, l4 = t & 3;
    float sk = 0.f, sq = 0.f;
    #pragma unroll
    for (int i = 0; i < 8; ++i) {
      float4 a  = *(const float4*)&sA[c][l4 * 32 + 4 * i];
      float4 qq = *(const float4*)&sQ[c][l4 * 32 + 4 * i];
      sk += a.x*a.x + a.y*a.y + a.z*a.z + a.w*a.w;
      sq += qq.x*qq.x + qq.y*qq.y + qq.z*qq.z + qq.w*qq.w;
    }
    sk += __shfl_xor(sk, 1, 64); sk += __shfl_xor(sk, 2, 64);
    sq += __shfl_xor(sq, 1, 64); sq += __shfl_xor(sq, 2, 64);
    const float rk = rsqrtf(sk + 1e-6f);
    const float rq = rsqrtf(sq + 1e-6f) * 0.08838834764831845f;  // * Dk^-0.5
    #pragma unroll
    for (int i = 0; i < 8; ++i) {
      float4 a  = *(const float4*)&sA[c][l4 * 32 + 4 * i];
      float4 qq = *(const float4*)&sQ[c][l4 * 32 + 4 * i];
      a.x*=rk; a.y*=rk; a.z*=rk; a.w*=rk;
      qq.x*=rq; qq.y*=rq; qq.z*=rq; qq.w*=rq;
      *(float4*)&sA[c][l4 * 32 + 4 * i] = a;
      *(float4*)&sQ[c][l4 * 32 + 4 * i] = qq;
    }
  }
  __syncthreads();

  // ---- M (strict lower, for solve) and attn (tril incl diag, to ws) ----
  {
    const int d = t & 63;
    const int w = t >> 6;                  // 0..3
    float ma[16], qa[16];
    #pragma unroll
    for (int kk = 0; kk < 16; ++kk) { ma[kk] = 0.f; qa[kk] = 0.f; }
    for (int dd = 0; dd < 128; dd += 4) {
      float4 va = *(const float4*)&sA[d][dd];
      #pragma unroll
      for (int kk = 0; kk < 16; ++kk) {
        const int c = w + 4 * kk;
        float4 ka = *(const float4*)&sA[c][dd];
        float4 qv = *(const float4*)&sQ[c][dd];
        ma[kk] += ka.x*va.x + ka.y*va.y + ka.z*va.z + ka.w*va.w;
        qa[kk] += qv.x*va.x + qv.y*va.y + qv.z*va.z + qv.w*va.w;
      }
    }
    float* attp = ws + OFF_ATT + (long)pl * 4096;
    #pragma unroll
    for (int kk = 0; kk < 16; ++kk) {
      const int c = w + 4 * kk;
      const float dec = (c >= d) ? expf(s_gc[c] - s_gc[d]) : 0.f;
      attp[c * 64 + d] = qa[kk] * dec;
      sM[c][d] = (c > d) ? ma[kk] * s_beta[c] * dec : 0.f;
    }
  }

  // ---- q_g (float4) and kd^T to ws ----
  {
    float* qgp  = ws + (long)pl * CH;               // OFF_QG == 0
    float* kdtp = ws + OFF_KDT + (long)pl * CH;
    #pragma unroll
    for (int i = 0; i < 8; ++i) {
      int o4 = t + 256 * i;
      int c = o4 >> 5, d = (o4 & 31) << 2;
      float4 a = *(const float4*)&sQ[c][d];
      const float e = s_egc[c];
      a.x*=e; a.y*=e; a.z*=e; a.w*=e;
      *(float4*)(qgp + (long)c * 128 + d) = a;
    }
    #pragma unroll
    for (int i = 0; i < 32; ++i) {
      int o = t + 256 * i;
      int d2 = o >> 6, c2 = o & 63;
      kdtp[o] = sA[c2][d2] * s_ekd[c2];     // kdT[d][c]
    }
  }
  __syncthreads();

  // ---- forward substitution (I+M) X = RHS, column-per-thread in registers ----
  {
    float X[64];
    const int j = t;
    if (j < 128) {
      #pragma unroll
      for (int i = 0; i < 64; ++i) X[i] = sA[i][j] * s_beta[i] * s_egc[i];
    } else {
      const int jj = j - 128;
      #pragma unroll
      for (int i = 0; i < 64; ++i)
        X[i] = v[base + (long)i * rowstr + jj] * s_beta[i];
    }
    #pragma unroll
    for (int i = 1; i < 64; ++i) {
      float s0 = 0.f, s1 = 0.f;
      #pragma unroll
      for (int l = 0; l < i - 1; l += 2) {
        s0 += sM[i][l]     * X[l];
        s1 += sM[i][l + 1] * X[l + 1];
      }
      if ((i & 1) != 0) s0 += sM[i][i - 1] * X[i - 1];
      X[i] = X[i] - s0 - s1;
    }
    float* dst = (j < 128) ? (ws + OFF_KC + (long)pl * CH + j)
                           : (ws + OFF_VC + (long)pl * CH + (j - 128));
    #pragma unroll
    for (int i = 0; i < 64; ++i) dst[(long)i * 128] = X[i];
  }
}

__global__ __launch_bounds__(512) void gdn_phaseB(
    const float* __restrict__ ws, float* __restrict__ out,
    int bh0, long ncp, int grp)
{
  const long OFF_KC  = ncp * CH;
  const long OFF_KDT = 2 * ncp * CH;
  const long OFF_VC  = 3 * ncp * CH;
  const long OFF_ATT = 4 * ncp * CH;
  const long OFF_GL  = 4 * ncp * CH + ncp * 4096;

  __shared__ float st[16][132];     // state[j][d]
  __shared__ float su[16][68];      // u[j][c]
  __shared__ float kc[64 * 128];    // k_cum (async-prefetched 1 chunk ahead)
  __shared__ float qg[64 * 128];
  __shared__ float kdt[128 * 64];
  __shared__ float att[64 * 64];

  const int t   = threadIdx.x;
  const int blk = blockIdx.x;
  const int bhl = blk % grp;        // same-bh blocks -> same XCD (round-robin)
  const int jb  = blk / grp;        // dv block (16 cols)
  const int bh  = bh0 + bhl;
  const int h   = bh % Hn;
  const int b   = bh / Hn;
  const int j   = t & 15;           // dv within block
  const int cg  = t >> 4;           // 0..31

  // prologue: KC(0) async, overlap with state zeroing
  {
    const float* src = ws + OFF_KC + (long)bhl * Nn * CH;
    #pragma unroll
    for (int i = 0; i < 4; ++i)
      gl_lds16(src + (t + 512 * i) * 4, kc + (t + 512 * i) * 4);
  }
  for (int i = t; i < 16 * 132; i += 512) (&st[0][0])[i] = 0.f;
  __syncthreads();

  for (int n = 0; n < Nn; ++n) {
    const long pl = (long)bhl * Nn + n;
    const float gl = ws[OFF_GL + pl];

    // issue QG(n), KDT(n), ATT(n) async (hidden under m1)
    {
      const float* s1 = ws + pl * CH;               // QG
      const float* s2 = ws + OFF_KDT + pl * CH;
      const float* s3 = ws + OFF_ATT + pl * 4096;
      #pragma unroll
      for (int i = 0; i < 4; ++i)
        gl_lds16(s1 + (t + 512 * i) * 4, qg + (t + 512 * i) * 4);
      #pragma unroll
      for (int i = 0; i < 4; ++i)
        gl_lds16(s2 + (t + 512 * i) * 4, kdt + (t + 512 * i) * 4);
      #pragma unroll
      for (int i = 0; i < 2; ++i)
        gl_lds16(s3 + (t + 512 * i) * 4, att + (t + 512 * i) * 4);
    }

    // m1: u = v_c - k_cum @ state   (kc resident from previous iter)
    {
      const int c0 = cg, c1 = cg + 32;
      const float* b0 = kc + c0 * 128;
      const float* b1 = kc + c1 * 128;
      float a0 = 0.f, a1 = 0.f;
      #pragma unroll
      for (int d = 0; d < 128; d += 4) {
        float4 sv = *(const float4*)&st[j][d];
        float4 x0 = *(const float4*)(b0 + d);
        float4 x1 = *(const float4*)(b1 + d);
        a0 += x0.x*sv.x + x0.y*sv.y + x0.z*sv.z + x0.w*sv.w;
        a1 += x1.x*sv.x + x1.y*sv.y + x1.z*sv.z + x1.w*sv.w;
      }
      su[j][c0] = ws[OFF_VC + pl * CH + c0 * 128 + jb * 16 + j] - a0;
      su[j][c1] = ws[OFF_VC + pl * CH + c1 * 128 + jb * 16 + j] - a1;
    }
    __syncthreads();   // drains QG/KDT/ATT; su visible; kc free

    // issue KC(n+1) async (hidden under m2+m3)
    if (n < Nn - 1) {
      const float* src = ws + OFF_KC + (pl + 1) * CH;
      #pragma unroll
      for (int i = 0; i < 4; ++i)
        gl_lds16(src + (t + 512 * i) * 4, kc + (t + 512 * i) * 4);
    }

    // m2: out = q_g @ state + attn @ u
    {
      const int c0 = cg, c1 = cg + 32;
      const float* b0 = qg + c0 * 128;
      const float* b1 = qg + c1 * 128;
      float a0 = 0.f, a1 = 0.f;
      #pragma unroll
      for (int d = 0; d < 128; d += 4) {
        float4 sv = *(const float4*)&st[j][d];
        float4 x0 = *(const float4*)(b0 + d);
        float4 x1 = *(const float4*)(b1 + d);
        a0 += x0.x*sv.x + x0.y*sv.y + x0.z*sv.z + x0.w*sv.w;
        a1 += x1.x*sv.x + x1.y*sv.y + x1.z*sv.z + x1.w*sv.w;
      }
      const float* ac0 = att + c0 * 64;
      const float* ac1 = att + c1 * 64;
      #pragma unroll
      for (int e = 0; e < 64; e += 4) {
        float4 uv = *(const float4*)&su[j][e];
        float4 v0 = *(const float4*)(ac0 + e);
        float4 v1 = *(const float4*)(ac1 + e);
        a0 += v0.x*uv.x + v0.y*uv.y + v0.z*uv.z + v0.w*uv.w;
        a1 += v1.x*uv.x + v1.y*uv.y + v1.z*uv.z + v1.w*uv.w;
      }
      const long obase = (((long)b * Sn + (long)n * Cn) * Hn + h) * DVn + jb * 16 + j;
      out[obase + (long)c0 * Hn * DVn] = a0;
      out[obase + (long)c1 * Hn * DVn] = a1;
    }
    __syncthreads();   // m2's st reads done before m3's st writes

    // m3: state = gl*state + kd^T @ u
    {
      float a0 = 0.f, a1 = 0.f, a2 = 0.f, a3 = 0.f;
      const float* bd0 = kdt + (cg +  0) * 64;
      const float* bd1 = kdt + (cg + 32) * 64;
      const float* bd2 = kdt + (cg + 64) * 64;
      const float* bd3 = kdt + (cg + 96) * 64;
      #pragma unroll
      for (int cc = 0; cc < 64; cc += 4) {
        float4 uv = *(const float4*)&su[j][cc];
        float4 k0 = *(const float4*)(bd0 + cc);
        float4 k1 = *(const float4*)(bd1 + cc);
        float4 k2 = *(const float4*)(bd2 + cc);
        float4 k3 = *(const float4*)(bd3 + cc);
        a0 += k0.x*uv.x + k0.y*uv.y + k0.z*uv.z + k0.w*uv.w;
        a1 += k1.x*uv.x + k1.y*uv.y + k1.z*uv.z + k1.w*uv.w;
        a2 += k2.x*uv.x + k2.y*uv.y + k2.z*uv.z + k2.w*uv.w;
        a3 += k3.x*uv.x + k3.y*uv.y + k3.z*uv.z + k3.w*uv.w;
      }
      st[j][cg +  0] = gl * st[j][cg +  0] + a0;
      st[j][cg + 32] = gl * st[j][cg + 32] + a1;
      st[j][cg + 64] = gl * st[j][cg + 64] + a2;
      st[j][cg + 96] = gl * st[j][cg + 96] + a3;
    }
    __syncthreads();   // drains KC(n+1); kdt/att/qg free for next issue
  }
}

extern "C" void kernel_launch(void* const* d_in, const int* in_sizes, int n_in,
                              void* d_out, int out_size, void* d_ws, size_t ws_size,
                              hipStream_t stream) {
  (void)in_sizes; (void)n_in; (void)out_size;
  const float* q    = (const float*)d_in[0];
  const float* k    = (const float*)d_in[1];
  const float* v    = (const float*)d_in[2];
  const float* g    = (const float*)d_in[3];
  const float* beta = (const float*)d_in[4];
  float* ws  = (float*)d_ws;
  float* out = (float*)d_out;

  const int NBH = Bn * Hn;                                // 32
  const long per_bh_bytes = (long)Nn * PER_CHUNK_F * 4;   // ~9.44 MB
  long fit = (long)(ws_size / (size_t)per_bh_bytes);
  int G = (int)(fit < 1 ? 1 : (fit > NBH ? NBH : fit));   // bh per pass
  const long ncp = (long)G * Nn;                          // chunk capacity/pass

  for (int bh0 = 0; bh0 < NBH; bh0 += G) {
    const int grp = (bh0 + G <= NBH) ? G : (NBH - bh0);
    hipLaunchKernelGGL(gdn_phaseA, dim3(grp * Nn), dim3(256), 0, stream,
                       q, k, v, g, beta, ws, bh0, ncp);
    hipLaunchKernelGGL(gdn_phaseB, dim3(grp * 8), dim3(512), 0, stream,
                       ws, out, bh0, ncp, grp);
  }
}

// Round 5
// 3116.824 us; speedup vs baseline: 1.4949x; 1.1223x over previous
//
#include <hip/hip_runtime.h>
#include <math.h>

// Gated delta-rule linear attention (Qwen3.5 GatedDeltaNet).
// Phase A: per-chunk preprocessing; emits operands pre-swizzled into MFMA
//   A-fragment layout as 3-way bf16 splits (h+m+l, ~fp32 accuracy with
//   6 MFMA products per logical matmul).
// Phase B: sequential scan, 1 wave per (bh, dv16); all GEMMs via
//   v_mfma_f32_16x16x32_bf16; state/u kept in f32 C-fragments, split 3-way
//   in-register for B-operands.

namespace {
constexpr int Bn = 2, Sn = 4096, Hn = 16, DKn = 128, DVn = 128, Cn = 64, Nn = 64;
// per-chunk ws block (bytes): KC h/m/l 3x16K, QG 3x16K, KDT 3x16K,
// ATT 3x8K, VC(f32, C-frag layout) 32K  => 200KB
constexpr long CHUNK_B = 204800;
constexpr long PER_BH_B = (long)Nn * CHUNK_B + Nn * 4;   // + GL floats
}

typedef __attribute__((ext_vector_type(4))) float f32x4;
typedef __attribute__((ext_vector_type(8))) short s16x8;
typedef __attribute__((ext_vector_type(4))) unsigned short u16x4;

__device__ __forceinline__ unsigned short bf16rn(float x) {
  unsigned u = __float_as_uint(x);
  u += 0x7FFFu + ((u >> 16) & 1u);
  return (unsigned short)(u >> 16);
}
__device__ __forceinline__ void tsplit(float x, unsigned short& h,
                                       unsigned short& m, unsigned short& l) {
  h = bf16rn(x);
  float r1 = x - __uint_as_float((unsigned)h << 16);
  m = bf16rn(r1);
  float r2 = r1 - __uint_as_float((unsigned)m << 16);
  l = bf16rn(r2);
}

__global__ __launch_bounds__(256, 1) void gdn_phaseA(
    const float* __restrict__ q, const float* __restrict__ k,
    const float* __restrict__ v, const float* __restrict__ g,
    const float* __restrict__ beta, char* __restrict__ wsb,
    int bh0, long ncp)
{
  __shared__ float sA[64][132];   // l2-normalized k  (later: VC stage)
  __shared__ float sQ[64][132];   // l2-normalized, scaled q (later: KC stage)
  __shared__ float sM[64][65];    // strict-lower M
  __shared__ float satt[64][68];  // attn (tril incl diag)
  __shared__ float s_gc[64], s_beta[64], s_egc[64], s_ekd[64];

  const int t  = threadIdx.x;
  const int pl = blockIdx.x;              // local chunk index within pass
  const int p  = bh0 * Nn + pl;
  const int n  = p % Nn;
  const int bh = p / Nn;
  const int h  = bh % Hn;
  const int b  = bh / Hn;
  const long base   = (((long)b * Sn + (long)n * Cn) * Hn + h) * DKn;
  const long rowstr = (long)Hn * DKn;                    // 2048
  const long gbase  = ((long)b * Sn + (long)n * Cn) * Hn + h;
  const long cb     = (long)pl * CHUNK_B;

  // ---- smalls ----
  if (t < 64) {
    s_beta[t] = beta[gbase + (long)t * Hn];
    sM[0][t]  = g[gbase + (long)t * Hn];
  }
  __syncthreads();
  if (t == 0) {
    float run = 0.f;
    #pragma unroll
    for (int c = 0; c < 64; ++c) { run += sM[0][c]; s_gc[c] = run; }
    ((float*)(wsb + ncp * CHUNK_B))[pl] = expf(run);     // GL
  }
  __syncthreads();
  if (t < 64) {
    s_egc[t] = expf(s_gc[t]);
    s_ekd[t] = expf(s_gc[63] - s_gc[t]);
  }

  // ---- load k, q ----
  #pragma unroll
  for (int i = 0; i < 8; ++i) {
    int idx = t + 256 * i;
    int c = idx >> 5;
    int d = (idx & 31) << 2;
    *(f32x4*)&sA[c][d] = *(const f32x4*)(k + base + (long)c * rowstr + d);
    *(f32x4*)&sQ[c][d] = *(const f32x4*)(q + base + (long)c * rowstr + d);
  }
  __syncthreads();

  // ---- l2norm (4 threads/row) ----
  {
    const int c = t >> 2, l4 = t & 3;
    float sk = 0.f, sq = 0.f;
    #pragma unroll
    for (int i = 0; i < 8; ++i) {
      f32x4 a  = *(const f32x4*)&sA[c][l4 * 32 + 4 * i];
      f32x4 qq = *(const f32x4*)&sQ[c][l4 * 32 + 4 * i];
      sk += a[0]*a[0] + a[1]*a[1] + a[2]*a[2] + a[3]*a[3];
      sq += qq[0]*qq[0] + qq[1]*qq[1] + qq[2]*qq[2] + qq[3]*qq[3];
    }
    sk += __shfl_xor(sk, 1, 64); sk += __shfl_xor(sk, 2, 64);
    sq += __shfl_xor(sq, 1, 64); sq += __shfl_xor(sq, 2, 64);
    const float rk = rsqrtf(sk + 1e-6f);
    const float rq = rsqrtf(sq + 1e-6f) * 0.08838834764831845f;
    #pragma unroll
    for (int i = 0; i < 8; ++i) {
      f32x4 a  = *(const f32x4*)&sA[c][l4 * 32 + 4 * i];
      f32x4 qq = *(const f32x4*)&sQ[c][l4 * 32 + 4 * i];
      a[0]*=rk; a[1]*=rk; a[2]*=rk; a[3]*=rk;
      qq[0]*=rq; qq[1]*=rq; qq[2]*=rq; qq[3]*=rq;
      *(f32x4*)&sA[c][l4 * 32 + 4 * i] = a;
      *(f32x4*)&sQ[c][l4 * 32 + 4 * i] = qq;
    }
  }
  __syncthreads();

  // ---- M (strict lower) and attn into LDS ----
  {
    const int d = t & 63;
    const int w = t >> 6;                  // 0..3
    float ma[16], qa[16];
    #pragma unroll
    for (int kk = 0; kk < 16; ++kk) { ma[kk] = 0.f; qa[kk] = 0.f; }
    for (int dd = 0; dd < 128; dd += 4) {
      f32x4 va = *(const f32x4*)&sA[d][dd];
      #pragma unroll
      for (int kk = 0; kk < 16; ++kk) {
        const int c = w + 4 * kk;
        f32x4 ka = *(const f32x4*)&sA[c][dd];
        f32x4 qv = *(const f32x4*)&sQ[c][dd];
        ma[kk] += ka[0]*va[0] + ka[1]*va[1] + ka[2]*va[2] + ka[3]*va[3];
        qa[kk] += qv[0]*va[0] + qv[1]*va[1] + qv[2]*va[2] + qv[3]*va[3];
      }
    }
    #pragma unroll
    for (int kk = 0; kk < 16; ++kk) {
      const int c = w + 4 * kk;
      const float dec = (c >= d) ? expf(s_gc[c] - s_gc[d]) : 0.f;
      satt[c][d] = qa[kk] * dec;
      sM[c][d] = (c > d) ? ma[kk] * s_beta[c] * dec : 0.f;
    }
  }
  __syncthreads();

  // ---- emissions in A-frag layout: o = tile*512 + lane*8 + idx ----
  // QG: A[64 c][128 dk], 16 tiles; val = sQ[row][k] * egc[row]
  {
    unsigned short* Hh = (unsigned short*)(wsb + cb + 49152);
    unsigned short* Mm = (unsigned short*)(wsb + cb + 65536);
    unsigned short* Ll = (unsigned short*)(wsb + cb + 81920);
    #pragma unroll
    for (int i = 0; i < 8; ++i) {
      int o = i * 1024 + t * 4;
      int tile = o >> 9, ln = (o >> 3) & 63;
      int row = (tile >> 2) * 16 + (ln & 15);
      int k0  = (tile & 3) * 32 + (ln >> 4) * 8 + (o & 7);
      float e = s_egc[row];
      f32x4 vv = *(const f32x4*)&sQ[row][k0];
      u16x4 hh, mm, ll; unsigned short h_, m_, l_;
      #pragma unroll
      for (int r = 0; r < 4; ++r) {
        tsplit(vv[r] * e, h_, m_, l_);
        hh[r] = h_; mm[r] = m_; ll[r] = l_;
      }
      *(u16x4*)(Hh + o) = hh; *(u16x4*)(Mm + o) = mm; *(u16x4*)(Ll + o) = ll;
    }
  }
  // KDT: A[128 dk][64 c], 16 tiles; val = sA[k][row] * ekd[k]
  {
    unsigned short* Hh = (unsigned short*)(wsb + cb + 98304);
    unsigned short* Mm = (unsigned short*)(wsb + cb + 114688);
    unsigned short* Ll = (unsigned short*)(wsb + cb + 131072);
    #pragma unroll
    for (int i = 0; i < 8; ++i) {
      int o = i * 1024 + t * 4;
      int tile = o >> 9, ln = (o >> 3) & 63;
      int row = (tile >> 1) * 16 + (ln & 15);
      int k0  = (tile & 1) * 32 + (ln >> 4) * 8 + (o & 7);
      u16x4 hh, mm, ll; unsigned short h_, m_, l_;
      #pragma unroll
      for (int r = 0; r < 4; ++r) {
        tsplit(sA[k0 + r][row] * s_ekd[k0 + r], h_, m_, l_);
        hh[r] = h_; mm[r] = m_; ll[r] = l_;
      }
      *(u16x4*)(Hh + o) = hh; *(u16x4*)(Mm + o) = mm; *(u16x4*)(Ll + o) = ll;
    }
  }
  // ATT: A[64 c][64 c], 8 tiles; val = satt[row][k]
  {
    unsigned short* Hh = (unsigned short*)(wsb + cb + 147456);
    unsigned short* Mm = (unsigned short*)(wsb + cb + 155648);
    unsigned short* Ll = (unsigned short*)(wsb + cb + 163840);
    #pragma unroll
    for (int i = 0; i < 4; ++i) {
      int o = i * 1024 + t * 4;
      int tile = o >> 9, ln = (o >> 3) & 63;
      int row = (tile >> 1) * 16 + (ln & 15);
      int k0  = (tile & 1) * 32 + (ln >> 4) * 8 + (o & 7);
      u16x4 hh, mm, ll; unsigned short h_, m_, l_;
      #pragma unroll
      for (int r = 0; r < 4; ++r) {
        tsplit(satt[row][k0 + r], h_, m_, l_);
        hh[r] = h_; mm[r] = m_; ll[r] = l_;
      }
      *(u16x4*)(Hh + o) = hh; *(u16x4*)(Mm + o) = mm; *(u16x4*)(Ll + o) = ll;
    }
  }

  // ---- forward substitution (I+M) X = RHS, column-per-thread ----
  float X[64];
  {
    const int j = t;
    if (j < 128) {
      #pragma unroll
      for (int i = 0; i < 64; ++i) X[i] = sA[i][j] * s_beta[i] * s_egc[i];
    } else {
      const int jj = j - 128;
      #pragma unroll
      for (int i = 0; i < 64; ++i)
        X[i] = v[base + (long)i * rowstr + jj] * s_beta[i];
    }
    #pragma unroll
    for (int i = 1; i < 64; ++i) {
      float s0 = 0.f, s1 = 0.f;
      #pragma unroll
      for (int l = 0; l < i - 1; l += 2) {
        s0 += sM[i][l]     * X[l];
        s1 += sM[i][l + 1] * X[l + 1];
      }
      if ((i & 1) != 0) s0 += sM[i][i - 1] * X[i - 1];
      X[i] = X[i] - s0 - s1;
    }
  }
  __syncthreads();   // all sA/sQ readers (emissions + X init) done

  // stage: KC columns into sQ, VC columns into sA
  if (t < 128) {
    #pragma unroll
    for (int c = 0; c < 64; ++c) sQ[c][t] = X[c];
  } else {
    #pragma unroll
    for (int c = 0; c < 64; ++c) sA[c][t - 128] = X[c];
  }
  __syncthreads();

  // KC: A[64 c][128 dk], 16 tiles from sQ
  {
    unsigned short* Hh = (unsigned short*)(wsb + cb);
    unsigned short* Mm = (unsigned short*)(wsb + cb + 16384);
    unsigned short* Ll = (unsigned short*)(wsb + cb + 32768);
    #pragma unroll
    for (int i = 0; i < 8; ++i) {
      int o = i * 1024 + t * 4;
      int tile = o >> 9, ln = (o >> 3) & 63;
      int row = (tile >> 2) * 16 + (ln & 15);
      int k0  = (tile & 3) * 32 + (ln >> 4) * 8 + (o & 7);
      f32x4 vv = *(const f32x4*)&sQ[row][k0];
      u16x4 hh, mm, ll; unsigned short h_, m_, l_;
      #pragma unroll
      for (int r = 0; r < 4; ++r) {
        tsplit(vv[r], h_, m_, l_);
        hh[r] = h_; mm[r] = m_; ll[r] = l_;
      }
      *(u16x4*)(Hh + o) = hh; *(u16x4*)(Mm + o) = mm; *(u16x4*)(Ll + o) = ll;
    }
  }
  // VC: C-frag layout f32 [jb 8][ct 4][lane 64][r 4] from sA
  {
    float* VC = (float*)(wsb + cb + 172032);
    #pragma unroll
    for (int i = 0; i < 8; ++i) {
      int o = i * 1024 + t * 4;
      int jbv = o >> 10, ct = (o >> 8) & 3, ln = (o >> 2) & 63;
      int c0 = ct * 16 + (ln >> 4) * 4;
      int jj = jbv * 16 + (ln & 15);
      f32x4 vv;
      vv[0] = sA[c0 + 0][jj]; vv[1] = sA[c0 + 1][jj];
      vv[2] = sA[c0 + 2][jj]; vv[3] = sA[c0 + 3][jj];
      *(f32x4*)(VC + o) = vv;
    }
  }
}

#define MM6(D, AH, AM, AL, BH, BM, BL)                                  \
  D = __builtin_amdgcn_mfma_f32_16x16x32_bf16(AH, BH, D, 0, 0, 0);      \
  D = __builtin_amdgcn_mfma_f32_16x16x32_bf16(AH, BM, D, 0, 0, 0);      \
  D = __builtin_amdgcn_mfma_f32_16x16x32_bf16(AM, BH, D, 0, 0, 0);      \
  D = __builtin_amdgcn_mfma_f32_16x16x32_bf16(AH, BL, D, 0, 0, 0);      \
  D = __builtin_amdgcn_mfma_f32_16x16x32_bf16(AL, BH, D, 0, 0, 0);      \
  D = __builtin_amdgcn_mfma_f32_16x16x32_bf16(AM, BM, D, 0, 0, 0);

__global__ __launch_bounds__(64, 1) void gdn_phaseB(
    const char* __restrict__ wsb, float* __restrict__ out,
    int bh0, long ncp, int grp)
{
  __shared__ unsigned short Sb_h[16][136];   // [dv j][dk]
  __shared__ unsigned short Sb_m[16][136];
  __shared__ unsigned short Sb_l[16][136];
  __shared__ unsigned short Ub_h[16][72];    // [dv j][c]
  __shared__ unsigned short Ub_m[16][72];
  __shared__ unsigned short Ub_l[16][72];

  const int lane = threadIdx.x;
  const int jrow = lane & 15;
  const int kgrp = lane >> 4;
  const int blk  = blockIdx.x;
  const int bhl  = blk % grp;
  const int jb   = blk / grp;
  const int bh   = bh0 + bhl;
  const int h    = bh % Hn;
  const int b    = bh / Hn;
  const float* GLp = (const float*)(wsb + ncp * CHUNK_B);

  f32x4 S[8];
  f32x4 zero = {0.f, 0.f, 0.f, 0.f};
  #pragma unroll
  for (int i = 0; i < 8; ++i) S[i] = zero;
  {
    for (int i = lane; i < 16 * 136; i += 64) {
      (&Sb_h[0][0])[i] = 0; (&Sb_m[0][0])[i] = 0; (&Sb_l[0][0])[i] = 0;
    }
  }

  float* outb = out + ((long)b * Sn) * (long)(Hn * DVn) + (long)h * DVn + jb * 16 + jrow;

  for (int n = 0; n < Nn; ++n) {
    const long pl = (long)bhl * Nn + n;
    const char* cbp = wsb + pl * CHUNK_B;
    const unsigned short* KCh = (const unsigned short*)cbp;
    const unsigned short* KCm = KCh + 8192;
    const unsigned short* KCl = KCh + 16384;
    const unsigned short* QGh = KCh + 24576;
    const unsigned short* QGm = KCh + 32768;
    const unsigned short* QGl = KCh + 40960;
    const unsigned short* KDh = KCh + 49152;
    const unsigned short* KDm = KCh + 57344;
    const unsigned short* KDl = KCh + 65536;
    const unsigned short* ATh = KCh + 73728;
    const unsigned short* ATm = KCh + 77824;
    const unsigned short* ATl = KCh + 81920;
    const float* VCp = (const float*)(cbp + 172032);
    const float gl = GLp[pl];

    // state B-frags (from previous chunk)
    s16x8 sbh[4], sbm[4], sbl[4];
    #pragma unroll
    for (int kt = 0; kt < 4; ++kt) {
      sbh[kt] = *(const s16x8*)&Sb_h[jrow][kt * 32 + kgrp * 8];
      sbm[kt] = *(const s16x8*)&Sb_m[jrow][kt * 32 + kgrp * 8];
      sbl[kt] = *(const s16x8*)&Sb_l[jrow][kt * 32 + kgrp * 8];
    }

    // m1: u = v_c - kc @ S
    f32x4 acc[4];
    #pragma unroll
    for (int i = 0; i < 4; ++i) acc[i] = zero;
    #pragma unroll
    for (int kt = 0; kt < 4; ++kt) {
      #pragma unroll
      for (int mt = 0; mt < 4; ++mt) {
        const int tl = mt * 4 + kt;
        s16x8 ah = *(const s16x8*)(KCh + (tl * 64 + lane) * 8);
        s16x8 am = *(const s16x8*)(KCm + (tl * 64 + lane) * 8);
        s16x8 al = *(const s16x8*)(KCl + (tl * 64 + lane) * 8);
        MM6(acc[mt], ah, am, al, sbh[kt], sbm[kt], sbl[kt]);
      }
    }
    #pragma unroll
    for (int ct = 0; ct < 4; ++ct) {
      f32x4 vcv = *(const f32x4*)(VCp + ((jb * 4 + ct) * 64 + lane) * 4);
      f32x4 uu = vcv - acc[ct];
      u16x4 hh, mm, ll; unsigned short h_, m_, l_;
      #pragma unroll
      for (int r = 0; r < 4; ++r) {
        tsplit(uu[r], h_, m_, l_);
        hh[r] = h_; mm[r] = m_; ll[r] = l_;
      }
      *(u16x4*)&Ub_h[jrow][ct * 16 + kgrp * 4] = hh;
      *(u16x4*)&Ub_m[jrow][ct * 16 + kgrp * 4] = mm;
      *(u16x4*)&Ub_l[jrow][ct * 16 + kgrp * 4] = ll;
    }

    // m2: out = qg @ S + att @ u
    f32x4 o4[4];
    #pragma unroll
    for (int i = 0; i < 4; ++i) o4[i] = zero;
    #pragma unroll
    for (int kt = 0; kt < 4; ++kt) {
      #pragma unroll
      for (int mt = 0; mt < 4; ++mt) {
        const int tl = mt * 4 + kt;
        s16x8 ah = *(const s16x8*)(QGh + (tl * 64 + lane) * 8);
        s16x8 am = *(const s16x8*)(QGm + (tl * 64 + lane) * 8);
        s16x8 al = *(const s16x8*)(QGl + (tl * 64 + lane) * 8);
        MM6(o4[mt], ah, am, al, sbh[kt], sbm[kt], sbl[kt]);
      }
    }
    s16x8 ubh[2], ubm[2], ubl[2];
    #pragma unroll
    for (int kt2 = 0; kt2 < 2; ++kt2) {
      ubh[kt2] = *(const s16x8*)&Ub_h[jrow][kt2 * 32 + kgrp * 8];
      ubm[kt2] = *(const s16x8*)&Ub_m[jrow][kt2 * 32 + kgrp * 8];
      ubl[kt2] = *(const s16x8*)&Ub_l[jrow][kt2 * 32 + kgrp * 8];
    }
    #pragma unroll
    for (int kt2 = 0; kt2 < 2; ++kt2) {
      #pragma unroll
      for (int mt = 0; mt < 4; ++mt) {
        const int tl = mt * 2 + kt2;
        s16x8 ah = *(const s16x8*)(ATh + (tl * 64 + lane) * 8);
        s16x8 am = *(const s16x8*)(ATm + (tl * 64 + lane) * 8);
        s16x8 al = *(const s16x8*)(ATl + (tl * 64 + lane) * 8);
        MM6(o4[mt], ah, am, al, ubh[kt2], ubm[kt2], ubl[kt2]);
      }
    }
    {
      float* orow = outb + (long)(n * 64) * (Hn * DVn);
      #pragma unroll
      for (int ct = 0; ct < 4; ++ct) {
        #pragma unroll
        for (int r = 0; r < 4; ++r)
          orow[(long)(ct * 16 + kgrp * 4 + r) * (Hn * DVn)] = o4[ct][r];
      }
    }

    // m3: S = gl*S + kdT @ u
    #pragma unroll
    for (int i = 0; i < 8; ++i) {
      S[i][0] *= gl; S[i][1] *= gl; S[i][2] *= gl; S[i][3] *= gl;
    }
    #pragma unroll
    for (int kt2 = 0; kt2 < 2; ++kt2) {
      #pragma unroll
      for (int dt = 0; dt < 8; ++dt) {
        const int tl = dt * 2 + kt2;
        s16x8 ah = *(const s16x8*)(KDh + (tl * 64 + lane) * 8);
        s16x8 am = *(const s16x8*)(KDm + (tl * 64 + lane) * 8);
        s16x8 al = *(const s16x8*)(KDl + (tl * 64 + lane) * 8);
        MM6(S[dt], ah, am, al, ubh[kt2], ubm[kt2], ubl[kt2]);
      }
    }
    // redistribute S -> Sb for next chunk
    #pragma unroll
    for (int dt = 0; dt < 8; ++dt) {
      u16x4 hh, mm, ll; unsigned short h_, m_, l_;
      #pragma unroll
      for (int r = 0; r < 4; ++r) {
        tsplit(S[dt][r], h_, m_, l_);
        hh[r] = h_; mm[r] = m_; ll[r] = l_;
      }
      *(u16x4*)&Sb_h[jrow][dt * 16 + kgrp * 4] = hh;
      *(u16x4*)&Sb_m[jrow][dt * 16 + kgrp * 4] = mm;
      *(u16x4*)&Sb_l[jrow][dt * 16 + kgrp * 4] = ll;
    }
  }
}

extern "C" void kernel_launch(void* const* d_in, const int* in_sizes, int n_in,
                              void* d_out, int out_size, void* d_ws, size_t ws_size,
                              hipStream_t stream) {
  (void)in_sizes; (void)n_in; (void)out_size;
  const float* q    = (const float*)d_in[0];
  const float* k    = (const float*)d_in[1];
  const float* v    = (const float*)d_in[2];
  const float* g    = (const float*)d_in[3];
  const float* beta = (const float*)d_in[4];
  char*  ws  = (char*)d_ws;
  float* out = (float*)d_out;

  const int NBH = Bn * Hn;                                // 32
  long fit = (long)(ws_size / (size_t)PER_BH_B);
  int G = (int)(fit < 1 ? 1 : (fit > NBH ? NBH : fit));   // bh per pass
  const long ncp = (long)G * Nn;                          // chunk capacity/pass

  for (int bh0 = 0; bh0 < NBH; bh0 += G) {
    const int grp = (bh0 + G <= NBH) ? G : (NBH - bh0);
    hipLaunchKernelGGL(gdn_phaseA, dim3(grp * Nn), dim3(256), 0, stream,
                       q, k, v, g, beta, ws, bh0, ncp);
    hipLaunchKernelGGL(gdn_phaseB, dim3(grp * 8), dim3(64), 0, stream,
                       ws, out, bh0, ncp, grp);
  }
}

// Round 6
// 1058.749 us; speedup vs baseline: 4.4009x; 2.9439x over previous
//
#include <hip/hip_runtime.h>
#include <math.h>

// Gated delta-rule linear attention (Qwen3.5 GatedDeltaNet).
// Phase A: per-chunk preprocessing; emits operands pre-swizzled into MFMA
//   A-fragment layout as 2-way f16 splits (h+l, 3 MFMA products ~ fp32).
// Phase B: sequential scan, 1 wave per (bh, dv16), barrier-free software
//   pipeline: operands staged to LDS via global_load_lds a chunk ahead,
//   guarded by counted vmcnt waits. All GEMMs via mfma_f32_16x16x32_f16.

namespace {
constexpr int Bn = 2, Sn = 4096, Hn = 16, DKn = 128, DVn = 128, Cn = 64, Nn = 64;
// per-chunk ws bytes: KC h/l 2x16K @0, QG @32768, KD @65536, AT @98304 (2x8K),
// VC f32 @114688 (32K) => 144KB
constexpr long CHUNK_B = 147456;
constexpr long PER_BH_B = (long)Nn * CHUNK_B + Nn * 4;   // + GL floats
}

typedef __attribute__((ext_vector_type(4))) float f32x4;
typedef __attribute__((ext_vector_type(8))) _Float16 f16x8;
typedef __attribute__((ext_vector_type(4))) _Float16 f16x4;

__device__ __forceinline__ void fsplit(float x, _Float16& h, _Float16& l) {
  h = (_Float16)x;
  l = (_Float16)(x - (float)h);
}

__device__ __forceinline__ void gl_lds16(const void* g, void* l) {
  __builtin_amdgcn_global_load_lds(
      (const __attribute__((address_space(1))) void*)g,
      (__attribute__((address_space(3))) void*)l, 16, 0, 0);
}

__global__ __launch_bounds__(256, 1) void gdn_phaseA(
    const float* __restrict__ q, const float* __restrict__ k,
    const float* __restrict__ v, const float* __restrict__ g,
    const float* __restrict__ beta, char* __restrict__ wsb,
    int bh0, long ncp)
{
  __shared__ float sA[64][132];   // l2-normalized k  (later: VC stage)
  __shared__ float sQ[64][132];   // l2-normalized, scaled q (later: KC stage)
  __shared__ float sM[64][65];    // strict-lower M
  __shared__ float satt[64][68];  // attn (tril incl diag)
  __shared__ float s_gc[64], s_beta[64], s_egc[64], s_ekd[64];

  const int t  = threadIdx.x;
  const int pl = blockIdx.x;              // local chunk index within pass
  const int p  = bh0 * Nn + pl;
  const int n  = p % Nn;
  const int bh = p / Nn;
  const int h  = bh % Hn;
  const int b  = bh / Hn;
  const long base   = (((long)b * Sn + (long)n * Cn) * Hn + h) * DKn;
  const long rowstr = (long)Hn * DKn;                    // 2048
  const long gbase  = ((long)b * Sn + (long)n * Cn) * Hn + h;
  const long cb     = (long)pl * CHUNK_B;

  // ---- smalls ----
  if (t < 64) {
    s_beta[t] = beta[gbase + (long)t * Hn];
    sM[0][t]  = g[gbase + (long)t * Hn];
  }
  __syncthreads();
  if (t == 0) {
    float run = 0.f;
    #pragma unroll
    for (int c = 0; c < 64; ++c) { run += sM[0][c]; s_gc[c] = run; }
    ((float*)(wsb + ncp * CHUNK_B))[pl] = expf(run);     // GL
  }
  __syncthreads();
  if (t < 64) {
    s_egc[t] = expf(s_gc[t]);
    s_ekd[t] = expf(s_gc[63] - s_gc[t]);
  }

  // ---- load k, q ----
  #pragma unroll
  for (int i = 0; i < 8; ++i) {
    int idx = t + 256 * i;
    int c = idx >> 5;
    int d = (idx & 31) << 2;
    *(f32x4*)&sA[c][d] = *(const f32x4*)(k + base + (long)c * rowstr + d);
    *(f32x4*)&sQ[c][d] = *(const f32x4*)(q + base + (long)c * rowstr + d);
  }
  __syncthreads();

  // ---- l2norm (4 threads/row) ----
  {
    const int c = t >> 2, l4 = t & 3;
    float sk = 0.f, sq = 0.f;
    #pragma unroll
    for (int i = 0; i < 8; ++i) {
      f32x4 a  = *(const f32x4*)&sA[c][l4 * 32 + 4 * i];
      f32x4 qq = *(const f32x4*)&sQ[c][l4 * 32 + 4 * i];
      sk += a[0]*a[0] + a[1]*a[1] + a[2]*a[2] + a[3]*a[3];
      sq += qq[0]*qq[0] + qq[1]*qq[1] + qq[2]*qq[2] + qq[3]*qq[3];
    }
    sk += __shfl_xor(sk, 1, 64); sk += __shfl_xor(sk, 2, 64);
    sq += __shfl_xor(sq, 1, 64); sq += __shfl_xor(sq, 2, 64);
    const float rk = rsqrtf(sk + 1e-6f);
    const float rq = rsqrtf(sq + 1e-6f) * 0.08838834764831845f;
    #pragma unroll
    for (int i = 0; i < 8; ++i) {
      f32x4 a  = *(const f32x4*)&sA[c][l4 * 32 + 4 * i];
      f32x4 qq = *(const f32x4*)&sQ[c][l4 * 32 + 4 * i];
      a[0]*=rk; a[1]*=rk; a[2]*=rk; a[3]*=rk;
      qq[0]*=rq; qq[1]*=rq; qq[2]*=rq; qq[3]*=rq;
      *(f32x4*)&sA[c][l4 * 32 + 4 * i] = a;
      *(f32x4*)&sQ[c][l4 * 32 + 4 * i] = qq;
    }
  }
  __syncthreads();

  // ---- M (strict lower) and attn into LDS ----
  {
    const int d = t & 63;
    const int w = t >> 6;                  // 0..3
    float ma[16], qa[16];
    #pragma unroll
    for (int kk = 0; kk < 16; ++kk) { ma[kk] = 0.f; qa[kk] = 0.f; }
    for (int dd = 0; dd < 128; dd += 4) {
      f32x4 va = *(const f32x4*)&sA[d][dd];
      #pragma unroll
      for (int kk = 0; kk < 16; ++kk) {
        const int c = w + 4 * kk;
        f32x4 ka = *(const f32x4*)&sA[c][dd];
        f32x4 qv = *(const f32x4*)&sQ[c][dd];
        ma[kk] += ka[0]*va[0] + ka[1]*va[1] + ka[2]*va[2] + ka[3]*va[3];
        qa[kk] += qv[0]*va[0] + qv[1]*va[1] + qv[2]*va[2] + qv[3]*va[3];
      }
    }
    #pragma unroll
    for (int kk = 0; kk < 16; ++kk) {
      const int c = w + 4 * kk;
      const float dec = (c >= d) ? expf(s_gc[c] - s_gc[d]) : 0.f;
      satt[c][d] = qa[kk] * dec;
      sM[c][d] = (c > d) ? ma[kk] * s_beta[c] * dec : 0.f;
    }
  }
  __syncthreads();

  // ---- emissions in A-frag layout: o = tile*512 + lane*8 + idx (f16 h/l) ----
  // QG: A[64 c][128 dk], 16 tiles; val = sQ[row][k] * egc[row]
  {
    _Float16* Hh = (_Float16*)(wsb + cb + 32768);
    _Float16* Ll = (_Float16*)(wsb + cb + 49152);
    #pragma unroll
    for (int i = 0; i < 8; ++i) {
      int o = i * 1024 + t * 4;
      int tile = o >> 9, ln = (o >> 3) & 63;
      int row = (tile >> 2) * 16 + (ln & 15);
      int k0  = (tile & 3) * 32 + (ln >> 4) * 8 + (o & 7);
      float e = s_egc[row];
      f32x4 vv = *(const f32x4*)&sQ[row][k0];
      f16x4 hh, ll; _Float16 h_, l_;
      #pragma unroll
      for (int r = 0; r < 4; ++r) {
        fsplit(vv[r] * e, h_, l_);
        hh[r] = h_; ll[r] = l_;
      }
      *(f16x4*)(Hh + o) = hh; *(f16x4*)(Ll + o) = ll;
    }
  }
  // KDT: A[128 dk][64 c], 16 tiles; val = sA[k][row] * ekd[k]
  {
    _Float16* Hh = (_Float16*)(wsb + cb + 65536);
    _Float16* Ll = (_Float16*)(wsb + cb + 81920);
    #pragma unroll
    for (int i = 0; i < 8; ++i) {
      int o = i * 1024 + t * 4;
      int tile = o >> 9, ln = (o >> 3) & 63;
      int row = (tile >> 1) * 16 + (ln & 15);
      int k0  = (tile & 1) * 32 + (ln >> 4) * 8 + (o & 7);
      f16x4 hh, ll; _Float16 h_, l_;
      #pragma unroll
      for (int r = 0; r < 4; ++r) {
        fsplit(sA[k0 + r][row] * s_ekd[k0 + r], h_, l_);
        hh[r] = h_; ll[r] = l_;
      }
      *(f16x4*)(Hh + o) = hh; *(f16x4*)(Ll + o) = ll;
    }
  }
  // ATT: A[64 c][64 c], 8 tiles; val = satt[row][k]
  {
    _Float16* Hh = (_Float16*)(wsb + cb + 98304);
    _Float16* Ll = (_Float16*)(wsb + cb + 106496);
    #pragma unroll
    for (int i = 0; i < 4; ++i) {
      int o = i * 1024 + t * 4;
      int tile = o >> 9, ln = (o >> 3) & 63;
      int row = (tile >> 1) * 16 + (ln & 15);
      int k0  = (tile & 1) * 32 + (ln >> 4) * 8 + (o & 7);
      f16x4 hh, ll; _Float16 h_, l_;
      #pragma unroll
      for (int r = 0; r < 4; ++r) {
        fsplit(satt[row][k0 + r], h_, l_);
        hh[r] = h_; ll[r] = l_;
      }
      *(f16x4*)(Hh + o) = hh; *(f16x4*)(Ll + o) = ll;
    }
  }

  // ---- forward substitution (I+M) X = RHS, column-per-thread ----
  float X[64];
  {
    const int j = t;
    if (j < 128) {
      #pragma unroll
      for (int i = 0; i < 64; ++i) X[i] = sA[i][j] * s_beta[i] * s_egc[i];
    } else {
      const int jj = j - 128;
      #pragma unroll
      for (int i = 0; i < 64; ++i)
        X[i] = v[base + (long)i * rowstr + jj] * s_beta[i];
    }
    #pragma unroll
    for (int i = 1; i < 64; ++i) {
      float s0 = 0.f, s1 = 0.f;
      #pragma unroll
      for (int l = 0; l < i - 1; l += 2) {
        s0 += sM[i][l]     * X[l];
        s1 += sM[i][l + 1] * X[l + 1];
      }
      if ((i & 1) != 0) s0 += sM[i][i - 1] * X[i - 1];
      X[i] = X[i] - s0 - s1;
    }
  }
  __syncthreads();   // all sA/sQ readers (emissions + X init) done

  // stage: KC columns into sQ, VC columns into sA
  if (t < 128) {
    #pragma unroll
    for (int c = 0; c < 64; ++c) sQ[c][t] = X[c];
  } else {
    #pragma unroll
    for (int c = 0; c < 64; ++c) sA[c][t - 128] = X[c];
  }
  __syncthreads();

  // KC: A[64 c][128 dk], 16 tiles from sQ
  {
    _Float16* Hh = (_Float16*)(wsb + cb);
    _Float16* Ll = (_Float16*)(wsb + cb + 16384);
    #pragma unroll
    for (int i = 0; i < 8; ++i) {
      int o = i * 1024 + t * 4;
      int tile = o >> 9, ln = (o >> 3) & 63;
      int row = (tile >> 2) * 16 + (ln & 15);
      int k0  = (tile & 3) * 32 + (ln >> 4) * 8 + (o & 7);
      f32x4 vv = *(const f32x4*)&sQ[row][k0];
      f16x4 hh, ll; _Float16 h_, l_;
      #pragma unroll
      for (int r = 0; r < 4; ++r) {
        fsplit(vv[r], h_, l_);
        hh[r] = h_; ll[r] = l_;
      }
      *(f16x4*)(Hh + o) = hh; *(f16x4*)(Ll + o) = ll;
    }
  }
  // VC: C-frag layout f32 [jb 8][ct 4][lane 64][r 4] from sA
  {
    float* VC = (float*)(wsb + cb + 114688);
    #pragma unroll
    for (int i = 0; i < 8; ++i) {
      int o = i * 1024 + t * 4;
      int jbv = o >> 10, ct = (o >> 8) & 3, ln = (o >> 2) & 63;
      int c0 = ct * 16 + (ln >> 4) * 4;
      int jj = jbv * 16 + (ln & 15);
      f32x4 vv;
      vv[0] = sA[c0 + 0][jj]; vv[1] = sA[c0 + 1][jj];
      vv[2] = sA[c0 + 2][jj]; vv[3] = sA[c0 + 3][jj];
      *(f32x4*)(VC + o) = vv;
    }
  }
}

#define MM3(D, AH, AL, BH, BL)                                        \
  D = __builtin_amdgcn_mfma_f32_16x16x32_f16(AH, BH, D, 0, 0, 0);     \
  D = __builtin_amdgcn_mfma_f32_16x16x32_f16(AH, BL, D, 0, 0, 0);     \
  D = __builtin_amdgcn_mfma_f32_16x16x32_f16(AL, BH, D, 0, 0, 0);

// counted vmcnt guard: every guarded region has >=84 younger VMEM issues,
// so vmcnt(48) guarantees the region's loads retired (oldest-first, m135).
#define VMW() do { asm volatile("s_waitcnt vmcnt(48)" ::: "memory"); \
                   __builtin_amdgcn_sched_barrier(0); } while (0)
#define LGW() do { asm volatile("s_waitcnt lgkmcnt(0)" ::: "memory"); \
                   __builtin_amdgcn_sched_barrier(0); } while (0)

#define STAGE(dst, srcB, nt) do {                                     \
    const char* s_ = (const char*)(srcB);                             \
    char* d_ = (char*)(dst);                                          \
    _Pragma("unroll")                                                 \
    for (int t_ = 0; t_ < (nt); ++t_)                                 \
      gl_lds16(s_ + t_ * 1024 + lane * 16, d_ + t_ * 1024 + lane * 16); \
  } while (0)

__global__ __launch_bounds__(64, 1) void gdn_phaseB(
    const char* __restrict__ wsb, float* __restrict__ out,
    int bh0, long ncp, int grp)
{
  __shared__ __align__(16) _Float16 sKC[2][2][8192];  // 64KB [buf][h/l]
  __shared__ __align__(16) _Float16 sQG[2][8192];     // 32KB [h/l]
  __shared__ __align__(16) _Float16 sKD[2][8192];     // 32KB
  __shared__ __align__(16) _Float16 sAT[2][4096];     // 16KB
  __shared__ __align__(16) _Float16 Sb[2][16][136];   // state B-frag bounce
  __shared__ __align__(16) _Float16 Ub[2][16][72];    // u B-frag bounce

  const int lane = threadIdx.x;
  const int jrow = lane & 15;
  const int kgrp = lane >> 4;
  const int blk  = blockIdx.x;
  const int bhl  = blk % grp;       // 8 jb-sharers of a bh land on one XCD
  const int jb   = blk / grp;
  const int bh   = bh0 + bhl;
  const int h    = bh % Hn;
  const int b    = bh / Hn;
  const float* GLp = (const float*)(wsb + ncp * CHUNK_B);

  f32x4 S[8];
  const f32x4 zero = {0.f, 0.f, 0.f, 0.f};
  #pragma unroll
  for (int i = 0; i < 8; ++i) S[i] = zero;
  for (int i = lane; i < 2 * 16 * 136; i += 64) (&Sb[0][0][0])[i] = (_Float16)0.f;

  // prologue: stage chunk 0 (KC->buf0, QG, AT, KD)
  const char* c0 = wsb + (long)bhl * Nn * CHUNK_B;
  STAGE(sKC[0][0], c0 +      0, 16); STAGE(sKC[0][1], c0 +  16384, 16);
  STAGE(sQG[0],    c0 +  32768, 16); STAGE(sQG[1],    c0 +  49152, 16);
  STAGE(sAT[0],    c0 +  98304,  8); STAGE(sAT[1],    c0 + 106496,  8);
  STAGE(sKD[0],    c0 +  65536, 16); STAGE(sKD[1],    c0 +  81920, 16);

  float* outb = out + ((long)b * Sn) * (long)(Hn * DVn) + (long)h * DVn + jb * 16 + jrow;

  int cur = 0;
  #pragma unroll 1
  for (int n = 0; n < Nn; ++n) {
    const long pl  = (long)bhl * Nn + n;
    const int  np  = (n + 1 < Nn) ? n + 1 : n;
    const long plp = (long)bhl * Nn + np;
    const char* cbp = wsb + pl * CHUNK_B;
    const char* cbn = wsb + plp * CHUNK_B;
    const float gl  = GLp[pl];

    // stage KC(n+1) into other buffer (double-buffered)
    STAGE(sKC[cur ^ 1][0], cbn +     0, 16);
    STAGE(sKC[cur ^ 1][1], cbn + 16384, 16);

    // VC reg loads (this chunk's jb slice)
    const float* VCp = (const float*)(cbp + 114688);
    f32x4 vcv[4];
    #pragma unroll
    for (int ct = 0; ct < 4; ++ct)
      vcv[ct] = *(const f32x4*)(VCp + ((jb * 4 + ct) * 64 + lane) * 4);

    VMW();  // KC(n) resident

    // state B-frags (zeros for n==0)
    f16x8 sbh[4], sbl[4];
    #pragma unroll
    for (int kt = 0; kt < 4; ++kt) {
      sbh[kt] = *(const f16x8*)&Sb[0][jrow][kt * 32 + kgrp * 8];
      sbl[kt] = *(const f16x8*)&Sb[1][jrow][kt * 32 + kgrp * 8];
    }

    // m1: acc = kc @ S
    f32x4 acc[4];
    #pragma unroll
    for (int i = 0; i < 4; ++i) acc[i] = zero;
    #pragma unroll
    for (int kt = 0; kt < 4; ++kt) {
      #pragma unroll
      for (int mt = 0; mt < 4; ++mt) {
        const int tl = mt * 4 + kt;
        f16x8 ah = *(const f16x8*)&sKC[cur][0][tl * 512 + lane * 8];
        f16x8 al = *(const f16x8*)&sKC[cur][1][tl * 512 + lane * 8];
        MM3(acc[mt], ah, al, sbh[kt], sbl[kt]);
      }
    }
    // u = v_c - acc -> Ub
    #pragma unroll
    for (int ct = 0; ct < 4; ++ct) {
      f32x4 uu = vcv[ct] - acc[ct];
      f16x4 hh, ll; _Float16 h_, l_;
      #pragma unroll
      for (int r = 0; r < 4; ++r) { fsplit(uu[r], h_, l_); hh[r] = h_; ll[r] = l_; }
      *(f16x4*)&Ub[0][jrow][ct * 16 + kgrp * 4] = hh;
      *(f16x4*)&Ub[1][jrow][ct * 16 + kgrp * 4] = ll;
    }

    VMW();  // QG(n) resident
    // m2a: o4 = qg @ S
    f32x4 o4[4];
    #pragma unroll
    for (int i = 0; i < 4; ++i) o4[i] = zero;
    #pragma unroll
    for (int kt = 0; kt < 4; ++kt) {
      #pragma unroll
      for (int mt = 0; mt < 4; ++mt) {
        const int tl = mt * 4 + kt;
        f16x8 ah = *(const f16x8*)&sQG[0][tl * 512 + lane * 8];
        f16x8 al = *(const f16x8*)&sQG[1][tl * 512 + lane * 8];
        MM3(o4[mt], ah, al, sbh[kt], sbl[kt]);
      }
    }
    LGW();  // QG(n) ds_reads retired -> safe to overwrite
    STAGE(sQG[0], cbn + 32768, 16); STAGE(sQG[1], cbn + 49152, 16);

    VMW();  // AT(n) resident
    // u B-frags
    f16x8 ubh[2], ubl[2];
    #pragma unroll
    for (int kt2 = 0; kt2 < 2; ++kt2) {
      ubh[kt2] = *(const f16x8*)&Ub[0][jrow][kt2 * 32 + kgrp * 8];
      ubl[kt2] = *(const f16x8*)&Ub[1][jrow][kt2 * 32 + kgrp * 8];
    }
    // m2b: o4 += att @ u
    #pragma unroll
    for (int kt2 = 0; kt2 < 2; ++kt2) {
      #pragma unroll
      for (int mt = 0; mt < 4; ++mt) {
        const int tl = mt * 2 + kt2;
        f16x8 ah = *(const f16x8*)&sAT[0][tl * 512 + lane * 8];
        f16x8 al = *(const f16x8*)&sAT[1][tl * 512 + lane * 8];
        MM3(o4[mt], ah, al, ubh[kt2], ubl[kt2]);
      }
    }
    LGW();
    STAGE(sAT[0], cbn + 98304, 8); STAGE(sAT[1], cbn + 106496, 8);

    // out stores
    {
      float* orow = outb + (long)(n * 64) * (Hn * DVn);
      #pragma unroll
      for (int ct = 0; ct < 4; ++ct) {
        #pragma unroll
        for (int r = 0; r < 4; ++r)
          orow[(long)(ct * 16 + kgrp * 4 + r) * (Hn * DVn)] = o4[ct][r];
      }
    }

    // m3: S = gl*S + kdT @ u
    #pragma unroll
    for (int i = 0; i < 8; ++i) {
      S[i][0] *= gl; S[i][1] *= gl; S[i][2] *= gl; S[i][3] *= gl;
    }
    VMW();  // KD(n) resident
    #pragma unroll
    for (int kt2 = 0; kt2 < 2; ++kt2) {
      #pragma unroll
      for (int dt = 0; dt < 8; ++dt) {
        const int tl = dt * 2 + kt2;
        f16x8 ah = *(const f16x8*)&sKD[0][tl * 512 + lane * 8];
        f16x8 al = *(const f16x8*)&sKD[1][tl * 512 + lane * 8];
        MM3(S[dt], ah, al, ubh[kt2], ubl[kt2]);
      }
    }
    LGW();
    STAGE(sKD[0], cbn + 65536, 16); STAGE(sKD[1], cbn + 81920, 16);

    // redistribute S -> Sb for next chunk
    #pragma unroll
    for (int dt = 0; dt < 8; ++dt) {
      f16x4 hh, ll; _Float16 h_, l_;
      #pragma unroll
      for (int r = 0; r < 4; ++r) { fsplit(S[dt][r], h_, l_); hh[r] = h_; ll[r] = l_; }
      *(f16x4*)&Sb[0][jrow][dt * 16 + kgrp * 4] = hh;
      *(f16x4*)&Sb[1][jrow][dt * 16 + kgrp * 4] = ll;
    }
    cur ^= 1;
  }
}

extern "C" void kernel_launch(void* const* d_in, const int* in_sizes, int n_in,
                              void* d_out, int out_size, void* d_ws, size_t ws_size,
                              hipStream_t stream) {
  (void)in_sizes; (void)n_in; (void)out_size;
  const float* q    = (const float*)d_in[0];
  const float* k    = (const float*)d_in[1];
  const float* v    = (const float*)d_in[2];
  const float* g    = (const float*)d_in[3];
  const float* beta = (const float*)d_in[4];
  char*  ws  = (char*)d_ws;
  float* out = (float*)d_out;

  const int NBH = Bn * Hn;                                // 32
  long fit = (long)(ws_size / (size_t)PER_BH_B);
  int G = (int)(fit < 1 ? 1 : (fit > NBH ? NBH : fit));   // bh per pass
  const long ncp = (long)G * Nn;                          // chunk capacity/pass

  for (int bh0 = 0; bh0 < NBH; bh0 += G) {
    const int grp = (bh0 + G <= NBH) ? G : (NBH - bh0);
    hipLaunchKernelGGL(gdn_phaseA, dim3(grp * Nn), dim3(256), 0, stream,
                       q, k, v, g, beta, ws, bh0, ncp);
    hipLaunchKernelGGL(gdn_phaseB, dim3(grp * 8), dim3(64), 0, stream,
                       ws, out, bh0, ncp, grp);
  }
}